// Round 8
// baseline (271.614 us; speedup 1.0000x reference)
//
#include <hip/hip_runtime.h>

#define N_NODES 20000
#define N_EDGES 320000
#define DIM 128
#define NLAYER 3
#define SCAN_BLK 1024
#define N_SCAN_BLKS ((N_NODES + SCAN_BLK - 1) / SCAN_BLK)  // 20
#define LDS_STRIDE 136

#define PREP_CASTW_BLKS 208
#define PREP_ZERO_BLKS 79
#define PREP_TOTAL (PREP_CASTW_BLKS + PREP_ZERO_BLKS)

typedef __attribute__((ext_vector_type(8))) short short8;
typedef __attribute__((ext_vector_type(4))) float f32x4;

__device__ inline ushort f2bf(float f) {
  uint u = __float_as_uint(f);
  uint r = (u + 0x7fffu + ((u >> 16) & 1u)) >> 16;
  return (ushort)r;
}
__device__ inline float bf2f(ushort u) { return __uint_as_float(((uint)u) << 16); }

// ---------------- fused prep: cast_w | zero degc ----------------
__global__ __launch_bounds__(256) void prep_kernel(
    const float* __restrict__ Wq, const float* __restrict__ Wk,
    const float* __restrict__ Wv, const float* __restrict__ Ws,
    const float* __restrict__ Wo, ushort* __restrict__ wt,
    int* __restrict__ degc) {
  int b = blockIdx.x;
  int t = threadIdx.x;
  if (b < PREP_CASTW_BLKS) {
    int z = b >> 4;
    int r = b & 15;
    int k0 = (r >> 2) * 32, n0 = (r & 3) * 32;
    const float* src;
    if (z < 12) {
      int l = z >> 2, j = z & 3;
      src = (j == 0 ? Wq : j == 1 ? Wk : j == 2 ? Wv : Ws) + (size_t)l * DIM * DIM;
    } else {
      src = Wo;
    }
    __shared__ float tile[32][33];
    int tx = t & 31, ty = t >> 5;
    #pragma unroll
    for (int i = 0; i < 32; i += 8)
      tile[ty + i][tx] = src[(size_t)(k0 + ty + i) * DIM + n0 + tx];
    __syncthreads();
    ushort* dst = wt + (size_t)z * DIM * DIM;
    #pragma unroll
    for (int i = 0; i < 32; i += 8)
      dst[(size_t)(n0 + ty + i) * DIM + k0 + tx] = f2bf(tile[tx][ty + i]);
  } else {
    int i = (b - PREP_CASTW_BLKS) * 256 + t;
    if (i < N_NODES) degc[i] = 0;
  }
}

// ---------------- CSR build ----------------

__global__ void count_deg_kernel(const int* __restrict__ ei, int* __restrict__ deg) {
  int e = blockIdx.x * 256 + threadIdx.x;
  if (e < N_EDGES) atomicAdd(&deg[ei[N_EDGES + e]], 1);
}

__global__ __launch_bounds__(SCAN_BLK) void scan1_kernel(const int* __restrict__ deg,
                                                         int* __restrict__ rowptr,
                                                         int* __restrict__ blksum) {
  __shared__ int wsum[16];
  int t = threadIdx.x, lane = t & 63, w = t >> 6;
  int i = blockIdx.x * SCAN_BLK + t;
  int val = (i < N_NODES) ? deg[i] : 0;
  int s = val;
  #pragma unroll
  for (int off = 1; off < 64; off <<= 1) {
    int u = __shfl_up(s, off);
    if (lane >= off) s += u;
  }
  if (lane == 63) wsum[w] = s;
  __syncthreads();
  if (t < 16) {
    int wv = wsum[t];
    int ss = wv;
    #pragma unroll
    for (int off = 1; off < 16; off <<= 1) {
      int u = __shfl_up(ss, off);
      if (t >= off) ss += u;
    }
    wsum[t] = ss - wv;
  }
  __syncthreads();
  int excl = wsum[w] + s - val;
  if (i < N_NODES) rowptr[i] = excl;
  if (t == SCAN_BLK - 1) blksum[blockIdx.x] = excl + val;
}

__global__ void scan2_kernel(int* __restrict__ blksum, int* __restrict__ rowptr) {
  int t = threadIdx.x;  // 64
  int val = (t < N_SCAN_BLKS) ? blksum[t] : 0;
  int s = val;
  #pragma unroll
  for (int off = 1; off < 64; off <<= 1) {
    int u = __shfl_up(s, off);
    if (t >= off) s += u;
  }
  if (t < N_SCAN_BLKS) blksum[t] = s - val;
  if (t == 63) rowptr[N_NODES] = s;
}

__global__ __launch_bounds__(SCAN_BLK) void scan3_kernel(int* __restrict__ rowptr,
                                                         const int* __restrict__ blksum,
                                                         int* __restrict__ degc) {
  int i = blockIdx.x * SCAN_BLK + threadIdx.x;
  if (i < N_NODES) {
    rowptr[i] += blksum[blockIdx.x];
    degc[i] = 0;
  }
}

__global__ void scatter_kernel(const int* __restrict__ ei, const int* __restrict__ rowptr,
                               int* __restrict__ cursor, int* __restrict__ csr_src) {
  int e = blockIdx.x * 256 + threadIdx.x;
  if (e < N_EDGES) {
    int d = ei[N_EDGES + e];
    int s = ei[e];
    int pos = atomicAdd(&cursor[d], 1);
    csr_src[rowptr[d] + pos] = s;
  }
}

// ---------------- bf16 MFMA GEMM: O_j = X @ W_j + b_j ----------------
// Output modes: 0 = bf16 row-major [r][DIM]; 1 = f32 row-major [r][DIM];
// 2 = kvp k-slot; 3 = kvp v-slot.
// kvp layout: [hp=head>>1][node][ (head&1)*16 + ch | +32 for v ]  (64 ushort rec)
template <int IN_F32>
__global__ __launch_bounds__(256) void gemm_mfma_kernel(
    const void* __restrict__ Xp, const ushort* __restrict__ WT,
    const float* __restrict__ B0, const float* __restrict__ B1,
    const float* __restrict__ B2, const float* __restrict__ B3,
    void* __restrict__ O0, void* __restrict__ O1, void* __restrict__ O2,
    void* __restrict__ O3, int m0, int m1, int m2, int m3) {
  __shared__ ushort As[128 * LDS_STRIDE];
  int mat = blockIdx.y;
  const ushort* Wt = WT + (size_t)mat * DIM * DIM;
  const float* bias;
  void* O;
  int mode;
  switch (mat) {
    case 0: bias = B0; O = O0; mode = m0; break;
    case 1: bias = B1; O = O1; mode = m1; break;
    case 2: bias = B2; O = O2; mode = m2; break;
    default: bias = B3; O = O3; mode = m3; break;
  }
  int t = threadIdx.x;
  int wid = t >> 6, lane = t & 63;
  int row0 = blockIdx.x * 128;
  int wr = wid >> 1, wc = wid & 1;
  int lr = lane & 15;
  int kc8 = (lane >> 4) * 8;

  if (IN_F32) {
    const float* Xf = (const float*)Xp;
    int rowi = t >> 5;
    int col4 = (t & 31) * 4;
    #pragma unroll
    for (int pass = 0; pass < 16; ++pass) {
      int row = pass * 8 + rowi;
      int gr = min(row0 + row, N_NODES - 1);
      float4 f = *(const float4*)(Xf + (size_t)gr * DIM + col4);
      ushort4 u;
      u.x = f2bf(f.x); u.y = f2bf(f.y); u.z = f2bf(f.z); u.w = f2bf(f.w);
      *(ushort4*)(As + row * LDS_STRIDE + col4) = u;
    }
  } else {
    const ushort* X = (const ushort*)Xp;
    int rowi = t >> 4;
    int col = (t & 15) * 8;
    #pragma unroll
    for (int pass = 0; pass < 8; ++pass) {
      int row = pass * 16 + rowi;
      int gr = min(row0 + row, N_NODES - 1);
      short8 val = *(const short8*)(X + (size_t)gr * DIM + col);
      *(short8*)(As + row * LDS_STRIDE + col) = val;
    }
  }
  __syncthreads();

  f32x4 acc[4][4];
  #pragma unroll
  for (int i = 0; i < 4; ++i)
    #pragma unroll
    for (int j = 0; j < 4; ++j) acc[i][j] = (f32x4){0.f, 0.f, 0.f, 0.f};

  #pragma unroll
  for (int ks = 0; ks < 4; ++ks) {
    short8 b[4];
    #pragma unroll
    for (int cf = 0; cf < 4; ++cf) {
      int c = wc * 64 + cf * 16 + lr;
      b[cf] = *(const short8*)(Wt + (size_t)c * DIM + ks * 32 + kc8);
    }
    #pragma unroll
    for (int rf = 0; rf < 4; ++rf) {
      int r = wr * 64 + rf * 16 + lr;
      short8 a = *(const short8*)(As + r * LDS_STRIDE + ks * 32 + kc8);
      #pragma unroll
      for (int cf = 0; cf < 4; ++cf)
        acc[rf][cf] = __builtin_amdgcn_mfma_f32_16x16x32_bf16(a, b[cf], acc[rf][cf], 0, 0, 0);
    }
  }

  // C/D layout: col = lane&15, row = (lane>>4)*4 + reg  [m89-verified]
  #pragma unroll
  for (int cf = 0; cf < 4; ++cf) {
    int c = wc * 64 + cf * 16 + lr;
    float bv = bias[c];
    int head = c >> 4, ch = c & 15;
    size_t kvoff = (size_t)(head >> 1) * ((size_t)N_NODES * 64) + (head & 1) * 16 + ch;
    #pragma unroll
    for (int rf = 0; rf < 4; ++rf) {
      #pragma unroll
      for (int reg = 0; reg < 4; ++reg) {
        int r = row0 + wr * 64 + rf * 16 + (lane >> 4) * 4 + reg;
        if (r < N_NODES) {
          float val = acc[rf][cf][reg] + bv;
          if (mode == 0)
            ((ushort*)O)[(size_t)r * DIM + c] = f2bf(val);
          else if (mode == 1)
            ((float*)O)[(size_t)r * DIM + c] = val;
          else if (mode == 2)
            ((ushort*)O)[kvoff + (size_t)r * 64] = f2bf(val);
          else
            ((ushort*)O)[kvoff + (size_t)r * 64 + 32] = f2bf(val);
        }
      }
    }
  }
}

// ---------------- attention gather: one wave per (node, head-pair) ----------------
// 128-thr blocks (2 waves = 2 nodes, SAME head-pair). hp = blockIdx&3; with the
// blockIdx%8 -> XCD round-robin, XCD x only touches slice x&3 (2.56MB, L2-fits).
// lane = (e = lane>>3, s = lane&7): s -> head (s>>2) of pair, quarter (s&3).
// Per lane: 8B k-quad + 8B v-quad from one 128B record; qq-reduce via shfl 1,2.
__global__ __launch_bounds__(128) void attn_gather_kernel(
    const ushort* __restrict__ q, const ushort* __restrict__ kvp,
    const int* __restrict__ rowptr, const int* __restrict__ csr_src,
    float* __restrict__ aout) {
  int wid = threadIdx.x >> 6, lane = threadIdx.x & 63;
  int bid = blockIdx.x;
  int hp = bid & 3;
  int n = (bid >> 2) * 2 + wid;
  int s = lane & 7, e = lane >> 3;

  ushort4 qu = *(const ushort4*)(q + (size_t)n * DIM + hp * 32 + s * 4);
  float q0 = bf2f(qu.x) * 0.25f, q1 = bf2f(qu.y) * 0.25f;
  float q2 = bf2f(qu.z) * 0.25f, q3 = bf2f(qu.w) * 0.25f;

  int s0 = rowptr[n];
  int deg = rowptr[n + 1] - s0;
  const ushort* base = kvp + (size_t)hp * ((size_t)N_NODES * 64);
  float dsum = 0.f, va0 = 0.f, va1 = 0.f, va2 = 0.f, va3 = 0.f;

  for (int b0 = 0; b0 < deg; b0 += 8) {
    int idx = b0 + e;
    bool valid = idx < deg;
    int src = csr_src[s0 + min(idx, deg - 1)];
    const ushort* rec = base + (size_t)src * 64 + s * 4;
    ushort4 ku = *(const ushort4*)rec;
    ushort4 vu = *(const ushort4*)(rec + 32);
    float part = q0 * bf2f(ku.x) + q1 * bf2f(ku.y) + q2 * bf2f(ku.z) + q3 * bf2f(ku.w);
    part += __shfl_xor(part, 1);
    part += __shfl_xor(part, 2);
    float ea = __expf(part);
    ea = valid ? ea : 0.f;
    dsum += ea;
    va0 = fmaf(ea, bf2f(vu.x), va0);
    va1 = fmaf(ea, bf2f(vu.y), va1);
    va2 = fmaf(ea, bf2f(vu.z), va2);
    va3 = fmaf(ea, bf2f(vu.w), va3);
  }
  #pragma unroll
  for (int off = 8; off <= 32; off <<= 1) {
    dsum += __shfl_xor(dsum, off);
    va0 += __shfl_xor(va0, off);
    va1 += __shfl_xor(va1, off);
    va2 += __shfl_xor(va2, off);
    va3 += __shfl_xor(va3, off);
  }
  if (e == 0) {
    float inv = 1.f / (dsum + 1e-16f);
    *(float4*)(aout + (size_t)n * DIM + hp * 32 + s * 4) =
        make_float4(va0 * inv, va1 * inv, va2 * inv, va3 * inv);
  }
}

// ---------------- epilogue: beta-skip + relu + residual + layernorm ----------------
__global__ __launch_bounds__(256) void attn_epi_kernel(
    const float* __restrict__ aout, const ushort* __restrict__ xr,
    const float* __restrict__ xres, const float* __restrict__ wbeta,
    const float* __restrict__ lng, const float* __restrict__ lnb,
    float* __restrict__ xnext, ushort* __restrict__ xnextb) {
  int w = threadIdx.x >> 6, lane = threadIdx.x & 63;
  int n = blockIdx.x * 4 + w;
  int c0 = lane * 2;
  float2 ov = *(const float2*)(aout + (size_t)n * DIM + c0);
  float o0 = ov.x, o1 = ov.y;

  ushort2 xru = *(const ushort2*)(xr + (size_t)n * DIM + c0);
  float xr0 = bf2f(xru.x), xr1 = bf2f(xru.y);
  float wa0 = wbeta[c0] + wbeta[2 * DIM + c0];
  float wa1 = wbeta[c0 + 1] + wbeta[2 * DIM + c0 + 1];
  float wb0 = wbeta[DIM + c0] - wbeta[2 * DIM + c0];
  float wb1 = wbeta[DIM + c0 + 1] - wbeta[2 * DIM + c0 + 1];
  float bs = o0 * wa0 + o1 * wa1 + xr0 * wb0 + xr1 * wb1;
  #pragma unroll
  for (int off = 1; off < 64; off <<= 1) bs += __shfl_xor(bs, off);
  float beta = 1.f / (1.f + __expf(-bs));
  float y0 = fmaxf(beta * xr0 + (1.f - beta) * o0, 0.f);
  float y1 = fmaxf(beta * xr1 + (1.f - beta) * o1, 0.f);
  float2 rv = *(const float2*)(xres + (size_t)n * DIM + c0);
  y0 += rv.x;
  y1 += rv.y;
  float s = y0 + y1;
  #pragma unroll
  for (int off = 1; off < 64; off <<= 1) s += __shfl_xor(s, off);
  float mu = s * (1.f / 128.f);
  float d0 = y0 - mu, d1 = y1 - mu;
  float vs = d0 * d0 + d1 * d1;
  #pragma unroll
  for (int off = 1; off < 64; off <<= 1) vs += __shfl_xor(vs, off);
  float rstd = rsqrtf(vs * (1.f / 128.f) + 1e-5f);
  float2 g = *(const float2*)(lng + c0);
  float2 b = *(const float2*)(lnb + c0);
  float out0 = d0 * rstd * g.x + b.x;
  float out1 = d1 * rstd * g.y + b.y;
  *(float2*)(xnext + (size_t)n * DIM + c0) = make_float2(out0, out1);
  ushort2 ob;
  ob.x = f2bf(out0);
  ob.y = f2bf(out1);
  *(ushort2*)(xnextb + (size_t)n * DIM + c0) = ob;
}

// ---------------- launch ----------------

extern "C" void kernel_launch(void* const* d_in, const int* in_sizes, int n_in,
                              void* d_out, int out_size, void* d_ws, size_t ws_size,
                              hipStream_t stream) {
  const float* x_in = (const float*)d_in[0];
  const int* ei = (const int*)d_in[1];
  const float* Wq = (const float*)d_in[2];
  const float* bq = (const float*)d_in[3];
  const float* Wk = (const float*)d_in[4];
  const float* bk = (const float*)d_in[5];
  const float* Wv = (const float*)d_in[6];
  const float* bv = (const float*)d_in[7];
  const float* Wsk = (const float*)d_in[8];
  const float* bsk = (const float*)d_in[9];
  const float* Wb = (const float*)d_in[10];
  const float* lng = (const float*)d_in[11];
  const float* lnb = (const float*)d_in[12];
  const float* Wout = (const float*)d_in[13];
  const float* bout = (const float*)d_in[14];
  float* out = (float*)d_out;

  char* p = (char*)d_ws;
  auto alloc = [&](size_t bytes) {
    char* r = p;
    p += (bytes + 255) & ~(size_t)255;
    return r;
  };
  const size_t NB2 = (size_t)N_NODES * DIM * 2;
  const size_t NB4 = (size_t)N_NODES * DIM * 4;
  ushort* xbb = (ushort*)alloc(NB2);      // bf16 x (written by epi for layers 1,2)
  ushort* qb = (ushort*)alloc(NB2);
  ushort* kvp = (ushort*)alloc(NB2 * 2);  // head-pair-major [4][N][64]
  ushort* xrb = (ushort*)alloc(NB2);
  float* aout = (float*)alloc(NB4);
  float* xf0 = (float*)alloc(NB4);
  float* xf1 = (float*)alloc(NB4);
  ushort* wt = (ushort*)alloc((size_t)13 * DIM * DIM * 2);
  int* rowptr = (int*)alloc((N_NODES + 1) * 4);
  int* degc = (int*)alloc(N_NODES * 4);
  int* blksum = (int*)alloc(64 * 4);
  int* csr_src = (int*)alloc(N_EDGES * 4);

  prep_kernel<<<PREP_TOTAL, 256, 0, stream>>>(Wq, Wk, Wv, Wsk, Wout, wt, degc);

  count_deg_kernel<<<(N_EDGES + 255) / 256, 256, 0, stream>>>(ei, degc);
  scan1_kernel<<<N_SCAN_BLKS, SCAN_BLK, 0, stream>>>(degc, rowptr, blksum);
  scan2_kernel<<<1, 64, 0, stream>>>(blksum, rowptr);
  scan3_kernel<<<N_SCAN_BLKS, SCAN_BLK, 0, stream>>>(rowptr, blksum, degc);
  scatter_kernel<<<(N_EDGES + 255) / 256, 256, 0, stream>>>(ei, rowptr, degc, csr_src);

  const int GX = (N_NODES + 127) / 128;  // 157
  const float* xres = x_in;
  float* xfbufs[NLAYER] = {xf0, xf1, xf0};
  for (int l = 0; l < NLAYER; ++l) {
    if (l == 0) {
      gemm_mfma_kernel<1><<<dim3(GX, 4), 256, 0, stream>>>(
          (const void*)x_in, wt + (size_t)l * 4 * DIM * DIM,
          bq + (size_t)l * DIM, bk + (size_t)l * DIM, bv + (size_t)l * DIM,
          bsk + (size_t)l * DIM,
          qb, kvp, kvp, xrb, 0, 2, 3, 0);
    } else {
      gemm_mfma_kernel<0><<<dim3(GX, 4), 256, 0, stream>>>(
          (const void*)xbb, wt + (size_t)l * 4 * DIM * DIM,
          bq + (size_t)l * DIM, bk + (size_t)l * DIM, bv + (size_t)l * DIM,
          bsk + (size_t)l * DIM,
          qb, kvp, kvp, xrb, 0, 2, 3, 0);
    }
    attn_gather_kernel<<<(N_NODES / 2) * 4, 128, 0, stream>>>(
        qb, kvp, rowptr, csr_src, aout);
    attn_epi_kernel<<<N_NODES / 4, 256, 0, stream>>>(
        aout, xrb, xres,
        Wb + (size_t)l * 3 * DIM, lng + (size_t)l * DIM, lnb + (size_t)l * DIM,
        xfbufs[l], xbb);
    xres = xfbufs[l];
  }
  gemm_mfma_kernel<0><<<dim3(GX, 1), 256, 0, stream>>>(
      (const void*)xbb, wt + (size_t)12 * DIM * DIM, bout, bout, bout, bout,
      out, out, out, out, 1, 1, 1, 1);
}

// Round 9
// 198.137 us; speedup vs baseline: 1.3708x; 1.3708x over previous
//
#include <hip/hip_runtime.h>

#define N_NODES 20000
#define N_EDGES 320000
#define DIM 128
#define NLAYER 3
#define SCAN_BLK 1024
#define N_SCAN_BLKS ((N_NODES + SCAN_BLK - 1) / SCAN_BLK)  // 20
#define LDS_STRIDE 136

#define PREP_CASTW_BLKS 208
#define PREP_ZERO_BLKS 79
#define PREP_TOTAL (PREP_CASTW_BLKS + PREP_ZERO_BLKS)

typedef __attribute__((ext_vector_type(8))) short short8;
typedef __attribute__((ext_vector_type(4))) float f32x4;
typedef __attribute__((ext_vector_type(2))) float f32x2;

__device__ inline ushort f2bf(float f) {
  uint u = __float_as_uint(f);
  uint r = (u + 0x7fffu + ((u >> 16) & 1u)) >> 16;
  return (ushort)r;
}
__device__ inline float bf2f(ushort u) { return __uint_as_float(((uint)u) << 16); }

// fp8 e4m3 (HW-native on gfx950, OCP) encode/decode
__device__ inline uint f2fp8(float f) {
  return __builtin_amdgcn_cvt_pk_fp8_f32(f, 0.f, 0, false) & 0xffu;
}
__device__ inline void fp8x4_to_f32(uint w, float* o) {
  f32x2 lo = __builtin_amdgcn_cvt_pk_f32_fp8(w, false);
  f32x2 hi = __builtin_amdgcn_cvt_pk_f32_fp8(w, true);
  o[0] = lo[0]; o[1] = lo[1]; o[2] = hi[0]; o[3] = hi[1];
}

// ---------------- fused prep: cast_w | zero degc ----------------
__global__ __launch_bounds__(256) void prep_kernel(
    const float* __restrict__ Wq, const float* __restrict__ Wk,
    const float* __restrict__ Wv, const float* __restrict__ Ws,
    const float* __restrict__ Wo, ushort* __restrict__ wt,
    int* __restrict__ degc) {
  int b = blockIdx.x;
  int t = threadIdx.x;
  if (b < PREP_CASTW_BLKS) {
    int z = b >> 4;
    int r = b & 15;
    int k0 = (r >> 2) * 32, n0 = (r & 3) * 32;
    const float* src;
    if (z < 12) {
      int l = z >> 2, j = z & 3;
      src = (j == 0 ? Wq : j == 1 ? Wk : j == 2 ? Wv : Ws) + (size_t)l * DIM * DIM;
    } else {
      src = Wo;
    }
    __shared__ float tile[32][33];
    int tx = t & 31, ty = t >> 5;
    #pragma unroll
    for (int i = 0; i < 32; i += 8)
      tile[ty + i][tx] = src[(size_t)(k0 + ty + i) * DIM + n0 + tx];
    __syncthreads();
    ushort* dst = wt + (size_t)z * DIM * DIM;
    #pragma unroll
    for (int i = 0; i < 32; i += 8)
      dst[(size_t)(n0 + ty + i) * DIM + k0 + tx] = f2bf(tile[tx][ty + i]);
  } else {
    int i = (b - PREP_CASTW_BLKS) * 256 + t;
    if (i < N_NODES) degc[i] = 0;
  }
}

// ---------------- CSR build ----------------

__global__ void count_deg_kernel(const int* __restrict__ ei, int* __restrict__ deg) {
  int e = blockIdx.x * 256 + threadIdx.x;
  if (e < N_EDGES) atomicAdd(&deg[ei[N_EDGES + e]], 1);
}

__global__ __launch_bounds__(SCAN_BLK) void scan1_kernel(const int* __restrict__ deg,
                                                         int* __restrict__ rowptr,
                                                         int* __restrict__ blksum) {
  __shared__ int wsum[16];
  int t = threadIdx.x, lane = t & 63, w = t >> 6;
  int i = blockIdx.x * SCAN_BLK + t;
  int val = (i < N_NODES) ? deg[i] : 0;
  int s = val;
  #pragma unroll
  for (int off = 1; off < 64; off <<= 1) {
    int u = __shfl_up(s, off);
    if (lane >= off) s += u;
  }
  if (lane == 63) wsum[w] = s;
  __syncthreads();
  if (t < 16) {
    int wv = wsum[t];
    int ss = wv;
    #pragma unroll
    for (int off = 1; off < 16; off <<= 1) {
      int u = __shfl_up(ss, off);
      if (t >= off) ss += u;
    }
    wsum[t] = ss - wv;
  }
  __syncthreads();
  int excl = wsum[w] + s - val;
  if (i < N_NODES) rowptr[i] = excl;
  if (t == SCAN_BLK - 1) blksum[blockIdx.x] = excl + val;
}

__global__ void scan2_kernel(int* __restrict__ blksum, int* __restrict__ rowptr) {
  int t = threadIdx.x;  // 64
  int val = (t < N_SCAN_BLKS) ? blksum[t] : 0;
  int s = val;
  #pragma unroll
  for (int off = 1; off < 64; off <<= 1) {
    int u = __shfl_up(s, off);
    if (t >= off) s += u;
  }
  if (t < N_SCAN_BLKS) blksum[t] = s - val;
  if (t == 63) rowptr[N_NODES] = s;
}

__global__ __launch_bounds__(SCAN_BLK) void scan3_kernel(int* __restrict__ rowptr,
                                                         const int* __restrict__ blksum,
                                                         int* __restrict__ degc) {
  int i = blockIdx.x * SCAN_BLK + threadIdx.x;
  if (i < N_NODES) {
    rowptr[i] += blksum[blockIdx.x];
    degc[i] = 0;
  }
}

__global__ void scatter_kernel(const int* __restrict__ ei, const int* __restrict__ rowptr,
                               int* __restrict__ cursor, int* __restrict__ csr_src) {
  int e = blockIdx.x * 256 + threadIdx.x;
  if (e < N_EDGES) {
    int d = ei[N_EDGES + e];
    int s = ei[e];
    int pos = atomicAdd(&cursor[d], 1);
    csr_src[rowptr[d] + pos] = s;
  }
}

// ---------------- bf16 MFMA GEMM: O_j = X @ W_j + b_j ----------------
// Output modes: 0 = bf16 row-major [r][DIM]; 1 = f32 row-major [r][DIM];
// 2 = fp8 kv record k-slot; 3 = fp8 kv record v-slot.
// kv record: [node][k ch0..127 (128B) | v ch0..127 (128B)] = 256B.
template <int IN_F32>
__global__ __launch_bounds__(256) void gemm_mfma_kernel(
    const void* __restrict__ Xp, const ushort* __restrict__ WT,
    const float* __restrict__ B0, const float* __restrict__ B1,
    const float* __restrict__ B2, const float* __restrict__ B3,
    void* __restrict__ O0, void* __restrict__ O1, void* __restrict__ O2,
    void* __restrict__ O3, int m0, int m1, int m2, int m3) {
  __shared__ ushort As[128 * LDS_STRIDE];
  int mat = blockIdx.y;
  const ushort* Wt = WT + (size_t)mat * DIM * DIM;
  const float* bias;
  void* O;
  int mode;
  switch (mat) {
    case 0: bias = B0; O = O0; mode = m0; break;
    case 1: bias = B1; O = O1; mode = m1; break;
    case 2: bias = B2; O = O2; mode = m2; break;
    default: bias = B3; O = O3; mode = m3; break;
  }
  int t = threadIdx.x;
  int wid = t >> 6, lane = t & 63;
  int row0 = blockIdx.x * 128;
  int wr = wid >> 1, wc = wid & 1;
  int lr = lane & 15;
  int kc8 = (lane >> 4) * 8;

  if (IN_F32) {
    const float* Xf = (const float*)Xp;
    int rowi = t >> 5;
    int col4 = (t & 31) * 4;
    #pragma unroll
    for (int pass = 0; pass < 16; ++pass) {
      int row = pass * 8 + rowi;
      int gr = min(row0 + row, N_NODES - 1);
      float4 f = *(const float4*)(Xf + (size_t)gr * DIM + col4);
      ushort4 u;
      u.x = f2bf(f.x); u.y = f2bf(f.y); u.z = f2bf(f.z); u.w = f2bf(f.w);
      *(ushort4*)(As + row * LDS_STRIDE + col4) = u;
    }
  } else {
    const ushort* X = (const ushort*)Xp;
    int rowi = t >> 4;
    int col = (t & 15) * 8;
    #pragma unroll
    for (int pass = 0; pass < 8; ++pass) {
      int row = pass * 16 + rowi;
      int gr = min(row0 + row, N_NODES - 1);
      short8 val = *(const short8*)(X + (size_t)gr * DIM + col);
      *(short8*)(As + row * LDS_STRIDE + col) = val;
    }
  }
  __syncthreads();

  f32x4 acc[4][4];
  #pragma unroll
  for (int i = 0; i < 4; ++i)
    #pragma unroll
    for (int j = 0; j < 4; ++j) acc[i][j] = (f32x4){0.f, 0.f, 0.f, 0.f};

  #pragma unroll
  for (int ks = 0; ks < 4; ++ks) {
    short8 b[4];
    #pragma unroll
    for (int cf = 0; cf < 4; ++cf) {
      int c = wc * 64 + cf * 16 + lr;
      b[cf] = *(const short8*)(Wt + (size_t)c * DIM + ks * 32 + kc8);
    }
    #pragma unroll
    for (int rf = 0; rf < 4; ++rf) {
      int r = wr * 64 + rf * 16 + lr;
      short8 a = *(const short8*)(As + r * LDS_STRIDE + ks * 32 + kc8);
      #pragma unroll
      for (int cf = 0; cf < 4; ++cf)
        acc[rf][cf] = __builtin_amdgcn_mfma_f32_16x16x32_bf16(a, b[cf], acc[rf][cf], 0, 0, 0);
    }
  }

  // C/D layout: col = lane&15, row = (lane>>4)*4 + reg  [m89-verified]
  #pragma unroll
  for (int cf = 0; cf < 4; ++cf) {
    int c = wc * 64 + cf * 16 + lr;
    float bv = bias[c];
    #pragma unroll
    for (int rf = 0; rf < 4; ++rf) {
      #pragma unroll
      for (int reg = 0; reg < 4; ++reg) {
        int r = row0 + wr * 64 + rf * 16 + (lane >> 4) * 4 + reg;
        if (r < N_NODES) {
          float val = acc[rf][cf][reg] + bv;
          if (mode == 0)
            ((ushort*)O)[(size_t)r * DIM + c] = f2bf(val);
          else if (mode == 1)
            ((float*)O)[(size_t)r * DIM + c] = val;
          else if (mode == 2)
            ((unsigned char*)O)[(size_t)r * 256 + c] = (unsigned char)f2fp8(val);
          else
            ((unsigned char*)O)[(size_t)r * 256 + 128 + c] = (unsigned char)f2fp8(val);
        }
      }
    }
  }
}

// ---------------- fused attention + beta-skip + relu + residual + layernorm --------
// r7 structure: 256-thr blocks, 4 waves, one dst node per wave; lane = (e=lane>>3,
// h=lane&7). kv record fp8: [node][k:128B | v:128B]; lane reads 16B k + 16B v per
// edge (its head's 16 channels). LDS transpose reduce; fused epilogue.
__global__ __launch_bounds__(256) void attn_fused_kernel(
    const ushort* __restrict__ q, const unsigned char* __restrict__ kv,
    const ushort* __restrict__ xr, const float* __restrict__ xres,
    const int* __restrict__ rowptr, const int* __restrict__ csr_src,
    const float* __restrict__ wbeta, const float* __restrict__ lng,
    const float* __restrict__ lnb, float* __restrict__ xnext,
    ushort* __restrict__ xnextb) {
  __shared__ float red[4][8][8][20];
  int w = threadIdx.x >> 6;
  int lane = threadIdx.x & 63;
  int n = blockIdx.x * 4 + w;
  int h = lane & 7, e = lane >> 3;

  const ushort* qrow = q + (size_t)n * DIM + h * 16;
  short8 q0 = *(const short8*)qrow;
  short8 q1 = *(const short8*)(qrow + 8);
  float qf[16];
  #pragma unroll
  for (int i = 0; i < 8; ++i) {
    qf[i] = bf2f((ushort)q0[i]) * 0.25f;  // 1/sqrt(C) folded into q
    qf[8 + i] = bf2f((ushort)q1[i]) * 0.25f;
  }

  int s0 = rowptr[n];
  int deg = rowptr[n + 1] - s0;
  float acc[16];
  #pragma unroll
  for (int i = 0; i < 16; ++i) acc[i] = 0.f;
  float dsum = 0.f;

  int src_n = (deg > 0) ? csr_src[s0 + min(e, deg - 1)] : 0;
  for (int base = 0; base < deg; base += 8) {
    int idx = base + e;
    bool valid = idx < deg;
    int src = src_n;
    if (base + 8 < deg)
      src_n = csr_src[s0 + min(base + 8 + e, deg - 1)];
    const unsigned char* rec = kv + (size_t)src * 256 + h * 16;
    uint4 ku = *(const uint4*)rec;
    uint4 vu = *(const uint4*)(rec + 128);
    float kf[16], vf[16];
    fp8x4_to_f32(ku.x, kf + 0);
    fp8x4_to_f32(ku.y, kf + 4);
    fp8x4_to_f32(ku.z, kf + 8);
    fp8x4_to_f32(ku.w, kf + 12);
    fp8x4_to_f32(vu.x, vf + 0);
    fp8x4_to_f32(vu.y, vf + 4);
    fp8x4_to_f32(vu.z, vf + 8);
    fp8x4_to_f32(vu.w, vf + 12);
    float p = 0.f;
    #pragma unroll
    for (int i = 0; i < 16; ++i) p = fmaf(qf[i], kf[i], p);
    float ea = __expf(p);
    ea = valid ? ea : 0.f;
    dsum += ea;
    #pragma unroll
    for (int i = 0; i < 16; ++i) acc[i] = fmaf(ea, vf[i], acc[i]);
  }

  // LDS transpose reduce over the 8 e-lanes (wave-private)
  {
    float* my = &red[w][e][h][0];
    *(float4*)(my + 0) = make_float4(acc[0], acc[1], acc[2], acc[3]);
    *(float4*)(my + 4) = make_float4(acc[4], acc[5], acc[6], acc[7]);
    *(float4*)(my + 8) = make_float4(acc[8], acc[9], acc[10], acc[11]);
    *(float4*)(my + 12) = make_float4(acc[12], acc[13], acc[14], acc[15]);
    my[16] = dsum;
  }
  asm volatile("s_waitcnt lgkmcnt(0)" ::: "memory");

  // epilogue: lane owns channels (2*lane, 2*lane+1)
  int c0 = lane * 2;
  int hh = lane >> 3, cc = (lane & 7) * 2;
  float o0 = 0.f, o1 = 0.f, den = 0.f;
  #pragma unroll
  for (int ee = 0; ee < 8; ++ee) {
    float2 tv = *(float2*)&red[w][ee][hh][cc];
    o0 += tv.x;
    o1 += tv.y;
    den += red[w][ee][hh][16];
  }
  float inv = 1.f / (den + 1e-16f);
  o0 *= inv;
  o1 *= inv;

  ushort2 xru = *(const ushort2*)(xr + (size_t)n * DIM + c0);
  float xr0 = bf2f(xru.x), xr1 = bf2f(xru.y);
  float wa0 = wbeta[c0] + wbeta[2 * DIM + c0];
  float wa1 = wbeta[c0 + 1] + wbeta[2 * DIM + c0 + 1];
  float wb0 = wbeta[DIM + c0] - wbeta[2 * DIM + c0];
  float wb1 = wbeta[DIM + c0 + 1] - wbeta[2 * DIM + c0 + 1];
  float bs = o0 * wa0 + o1 * wa1 + xr0 * wb0 + xr1 * wb1;
  #pragma unroll
  for (int off = 1; off < 64; off <<= 1) bs += __shfl_xor(bs, off);
  float beta = 1.f / (1.f + __expf(-bs));
  float y0 = fmaxf(beta * xr0 + (1.f - beta) * o0, 0.f);
  float y1 = fmaxf(beta * xr1 + (1.f - beta) * o1, 0.f);
  float2 rv = *(const float2*)(xres + (size_t)n * DIM + c0);
  y0 += rv.x;
  y1 += rv.y;
  float s = y0 + y1;
  #pragma unroll
  for (int off = 1; off < 64; off <<= 1) s += __shfl_xor(s, off);
  float mu = s * (1.f / 128.f);
  float d0 = y0 - mu, d1 = y1 - mu;
  float vs = d0 * d0 + d1 * d1;
  #pragma unroll
  for (int off = 1; off < 64; off <<= 1) vs += __shfl_xor(vs, off);
  float rstd = rsqrtf(vs * (1.f / 128.f) + 1e-5f);
  float2 g = *(const float2*)(lng + c0);
  float2 b = *(const float2*)(lnb + c0);
  float out0 = d0 * rstd * g.x + b.x;
  float out1 = d1 * rstd * g.y + b.y;
  *(float2*)(xnext + (size_t)n * DIM + c0) = make_float2(out0, out1);
  ushort2 ob;
  ob.x = f2bf(out0);
  ob.y = f2bf(out1);
  *(ushort2*)(xnextb + (size_t)n * DIM + c0) = ob;
}

// ---------------- launch ----------------

extern "C" void kernel_launch(void* const* d_in, const int* in_sizes, int n_in,
                              void* d_out, int out_size, void* d_ws, size_t ws_size,
                              hipStream_t stream) {
  const float* x_in = (const float*)d_in[0];
  const int* ei = (const int*)d_in[1];
  const float* Wq = (const float*)d_in[2];
  const float* bq = (const float*)d_in[3];
  const float* Wk = (const float*)d_in[4];
  const float* bk = (const float*)d_in[5];
  const float* Wv = (const float*)d_in[6];
  const float* bv = (const float*)d_in[7];
  const float* Wsk = (const float*)d_in[8];
  const float* bsk = (const float*)d_in[9];
  const float* Wb = (const float*)d_in[10];
  const float* lng = (const float*)d_in[11];
  const float* lnb = (const float*)d_in[12];
  const float* Wout = (const float*)d_in[13];
  const float* bout = (const float*)d_in[14];
  float* out = (float*)d_out;

  char* p = (char*)d_ws;
  auto alloc = [&](size_t bytes) {
    char* r = p;
    p += (bytes + 255) & ~(size_t)255;
    return r;
  };
  const size_t NB2 = (size_t)N_NODES * DIM * 2;
  const size_t NB4 = (size_t)N_NODES * DIM * 4;
  ushort* xbb = (ushort*)alloc(NB2);
  ushort* qb = (ushort*)alloc(NB2);
  unsigned char* kvb = (unsigned char*)alloc((size_t)N_NODES * 256);  // fp8 [node][k|v]
  ushort* xrb = (ushort*)alloc(NB2);
  float* xf0 = (float*)alloc(NB4);
  float* xf1 = (float*)alloc(NB4);
  ushort* wt = (ushort*)alloc((size_t)13 * DIM * DIM * 2);
  int* rowptr = (int*)alloc((N_NODES + 1) * 4);
  int* degc = (int*)alloc(N_NODES * 4);
  int* blksum = (int*)alloc(64 * 4);
  int* csr_src = (int*)alloc(N_EDGES * 4);

  prep_kernel<<<PREP_TOTAL, 256, 0, stream>>>(Wq, Wk, Wv, Wsk, Wout, wt, degc);

  count_deg_kernel<<<(N_EDGES + 255) / 256, 256, 0, stream>>>(ei, degc);
  scan1_kernel<<<N_SCAN_BLKS, SCAN_BLK, 0, stream>>>(degc, rowptr, blksum);
  scan2_kernel<<<1, 64, 0, stream>>>(blksum, rowptr);
  scan3_kernel<<<N_SCAN_BLKS, SCAN_BLK, 0, stream>>>(rowptr, blksum, degc);
  scatter_kernel<<<(N_EDGES + 255) / 256, 256, 0, stream>>>(ei, rowptr, degc, csr_src);

  const int GX = (N_NODES + 127) / 128;  // 157
  const float* xres = x_in;
  float* xfbufs[NLAYER] = {xf0, xf1, xf0};
  for (int l = 0; l < NLAYER; ++l) {
    if (l == 0) {
      gemm_mfma_kernel<1><<<dim3(GX, 4), 256, 0, stream>>>(
          (const void*)x_in, wt + (size_t)l * 4 * DIM * DIM,
          bq + (size_t)l * DIM, bk + (size_t)l * DIM, bv + (size_t)l * DIM,
          bsk + (size_t)l * DIM,
          qb, kvb, kvb, xrb, 0, 2, 3, 0);
    } else {
      gemm_mfma_kernel<0><<<dim3(GX, 4), 256, 0, stream>>>(
          (const void*)xbb, wt + (size_t)l * 4 * DIM * DIM,
          bq + (size_t)l * DIM, bk + (size_t)l * DIM, bv + (size_t)l * DIM,
          bsk + (size_t)l * DIM,
          qb, kvb, kvb, xrb, 0, 2, 3, 0);
    }
    attn_fused_kernel<<<N_NODES / 4, 256, 0, stream>>>(
        qb, kvb, xrb, xres, rowptr, csr_src,
        Wb + (size_t)l * 3 * DIM, lng + (size_t)l * DIM, lnb + (size_t)l * DIM,
        xfbufs[l], xbb);
    xres = xfbufs[l];
  }
  gemm_mfma_kernel<0><<<dim3(GX, 1), 256, 0, stream>>>(
      (const void*)xbb, wt + (size_t)12 * DIM * DIM, bout, bout, bout, bout,
      out, out, out, out, 1, 1, 1, 1);
}